// Round 4
// baseline (18110.173 us; speedup 1.0000x reference)
//
#include <hip/hip_runtime.h>
#include <stdint.h>

// SpikingNetwork B=128 T=128 I=1024 dims 2048/2048/1024, beta=0.9, thr=1.0.
// R4: full FP32 vector-FMA compute (bf16 MFMA proven unable to reproduce exact
// spike decisions in R3 — any flip = absmax 1.0). Persistent layer-pipelined
// kernel: A=L0 (bids 0..127), B=L1 (128..383), C=L2 (384..511); 512 x 128 thr;
// LDS 70,144 B -> exactly 2 blocks/CU, all 512 co-resident (required: spin-flags).
// Spikes cross layers as bitmasks; fp32 k-split partials; agent-scope atomics.

#define TT   128
#define NB   128
#define DD2  1024

// ws layout (u32 units)
#define SPK0_OFF 0u
#define SPK1_OFF (128u*128u*64u)                 // 1,048,576
#define PART_OFF (2u*128u*128u*64u)              // 2,097,152
#define NHELP    352u
#define FLG_OFF  (PART_OFF + NHELP*4096u)        // 3,538,944
#define WS_NEED_BYTES ((size_t)(FLG_OFF + 1280u) * 4u)   // 14,160,896

__device__ __forceinline__ void wait_ge(uint32_t* p, uint32_t tgt){
  while (__hip_atomic_load(p, __ATOMIC_ACQUIRE, __HIP_MEMORY_SCOPE_AGENT) < tgt)
    __builtin_amdgcn_s_sleep(1);
}

__global__ void sentinel_kernel(float* o){ o[0] = 42.0f; }   // ws-too-small marker

__global__ __launch_bounds__(128, 1) void snn_kernel(
    const float* __restrict__ x,
    const float* __restrict__ W0, const float* __restrict__ b0,
    const float* __restrict__ W1, const float* __restrict__ b1,
    const float* __restrict__ W2, const float* __restrict__ b2,
    float* __restrict__ out, uint32_t* __restrict__ ws)
{
  __shared__ __align__(16) float lA[128][68];   // [k][m], 34,816 B
  __shared__ __align__(16) float lB[128][68];   // [k][n], 34,816 B
  __shared__ uint32_t lBits[128];               // 64 rows x 2 spike words

  const int tid = threadIdx.x;
  const int tm = tid & 15;          // m-group: rows tm*4 .. +3
  const int tn = tid >> 4;          // n-group: cols tn*8 .. +7
  const int bid = blockIdx.x;

  uint32_t* spikes0  = ws + SPK0_OFF;
  uint32_t* spikes1  = ws + SPK1_OFF;
  float*    partials = (float*)(ws + PART_OFF);   // [NHELP][4096]
  uint32_t* flg   = ws + FLG_OFF;
  uint32_t* pflag = flg;          // [512] helper->owner: partials for t ready (t+1)
  uint32_t* oflag = flg + 512;    // [512] owner->helpers: consumed through t (t+1)
  uint32_t* done0 = flg + 1024;   // [128] L0 owner tiles done for t (target 64)
  uint32_t* done1 = flg + 1152;   // [128] same for L1

  int group, kp, ksp, m0, n0, K, tl, hslot;
  const float *Wl, *bl; const uint32_t* spkIn; uint32_t* spkOut;
  uint32_t *dIn, *dOut;
  if (bid < 128) {        // L0: out 128x2048, K=1024, ksplit 2
    group=0; ksp=2; int rel=bid;      kp=rel&1; tl=rel>>1;
    m0=(tl>>5)*64; n0=(tl&31)*64; K=1024; Wl=W0; bl=b0; spkIn=nullptr;  spkOut=spikes0; dIn=nullptr; dOut=done0;
    hslot = tl;
  } else if (bid < 384) { // L1: out 128x2048, K=2048, ksplit 4
    group=1; ksp=4; int rel=bid-128;  kp=rel&3; tl=rel>>2;
    m0=(tl>>5)*64; n0=(tl&31)*64; K=2048; Wl=W1; bl=b1; spkIn=spikes0; spkOut=spikes1; dIn=done0;  dOut=done1;
    hslot = 64 + tl*3 + (kp-1);
  } else {                // L2: out 128x1024, K=2048, ksplit 4
    group=2; ksp=4; int rel=bid-384;  kp=rel&3; tl=rel>>2;
    m0=(tl>>4)*64; n0=(tl&15)*64; K=2048; Wl=W2; bl=b2; spkIn=spikes1; spkOut=nullptr; dIn=done1;  dOut=nullptr;
    hslot = 256 + tl*3 + (kp-1);
  }
  const int K0 = kp*512;
  const bool owner = (kp == 0);

  float bias[8];
  #pragma unroll
  for (int c = 0; c < 8; ++c) bias[c] = bl[n0 + tn*8 + c];

  float vst[4][8];   // membrane potential in registers across all T (owners)
  #pragma unroll
  for (int r = 0; r < 4; ++r)
    #pragma unroll
    for (int c = 0; c < 8; ++c) vst[r][c] = 0.f;

  for (int t = 0; t < TT; ++t) {
    if (dIn) {  // previous layer's spikes for this t must be complete
      if (tid == 0) wait_ge(&dIn[t], 64u);
      __syncthreads();
    }
    float acc[4][8];
    #pragma unroll
    for (int r = 0; r < 4; ++r)
      #pragma unroll
      for (int c = 0; c < 8; ++c) acc[r][c] = 0.f;

    for (int ch = 0; ch < 4; ++ch) {            // 4 k-chunks of 128 in this 512 k-part
      const int kb = K0 + ch*128;
      // --- stage B: weights [n][K] -> lB[k][n]
      #pragma unroll
      for (int it = 0; it < 16; ++it) {
        int f4 = tid + it*128;
        int nrow = f4 >> 5, kq = f4 & 31;
        float4 w = *(const float4*)(Wl + (size_t)(n0+nrow)*K + kb + kq*4);
        lB[kq*4+0][nrow] = w.x; lB[kq*4+1][nrow] = w.y;
        lB[kq*4+2][nrow] = w.z; lB[kq*4+3][nrow] = w.w;
      }
      // --- stage A
      if (group == 0) {  // x[b, t, k] -> lA[k][m]
        #pragma unroll
        for (int it = 0; it < 16; ++it) {
          int f4 = tid + it*128;
          int row = f4 >> 5, kq = f4 & 31;
          float4 v = *(const float4*)(x + ((size_t)(m0+row)*TT + t)*1024 + kb + kq*4);
          lA[kq*4+0][row] = v.x; lA[kq*4+1][row] = v.y;
          lA[kq*4+2][row] = v.z; lA[kq*4+3][row] = v.w;
        }
      } else {           // spike bitmask -> {0,1} f32 in lA[k][m]
        #pragma unroll
        for (int it = 0; it < 2; ++it) {
          int wid = tid + it*128;
          int row = wid >> 2, wsub = wid & 3;
          uint32_t bits = __hip_atomic_load((uint32_t*)&spkIn[((size_t)t*NB + m0+row)*64 + (kb>>5) + wsub],
                                            __ATOMIC_RELAXED, __HIP_MEMORY_SCOPE_AGENT);
          #pragma unroll
          for (int j = 0; j < 32; ++j)
            lA[wsub*32 + j][row] = (bits >> j) & 1u ? 1.0f : 0.0f;
        }
      }
      __syncthreads();
      // --- FMA micro-kernel: 128 k x (4m x 8n)
      #pragma unroll 8
      for (int kk = 0; kk < 128; ++kk) {
        const float4 a  = *(const float4*)&lA[kk][tm*4];
        const float4 u0 = *(const float4*)&lB[kk][tn*8];
        const float4 u1 = *(const float4*)&lB[kk][tn*8+4];
        const float ar[4] = {a.x, a.y, a.z, a.w};
        const float bc[8] = {u0.x, u0.y, u0.z, u0.w, u1.x, u1.y, u1.z, u1.w};
        #pragma unroll
        for (int r = 0; r < 4; ++r)
          #pragma unroll
          for (int c = 0; c < 8; ++c)
            acc[r][c] += ar[r] * bc[c];
        }
      __syncthreads();
    }

    if (!owner) {
      // single-buffered partials: wait until owner consumed t-1 before overwrite
      const int ob = bid - kp;
      if (t >= 1) { if (tid == 0) wait_ge(&oflag[ob], (uint32_t)t); __syncthreads(); }
      uint64_t* pb = (uint64_t*)(partials + (size_t)hslot*4096) + tid*16;
      #pragma unroll
      for (int r = 0; r < 4; ++r)
        #pragma unroll
        for (int cq = 0; cq < 2; ++cq) {
          union { float f[4]; uint64_t u[2]; } cv;
          cv.f[0]=acc[r][cq*4+0]; cv.f[1]=acc[r][cq*4+1];
          cv.f[2]=acc[r][cq*4+2]; cv.f[3]=acc[r][cq*4+3];
          __hip_atomic_store(&pb[r*4+cq*2+0], cv.u[0], __ATOMIC_RELAXED, __HIP_MEMORY_SCOPE_AGENT);
          __hip_atomic_store(&pb[r*4+cq*2+1], cv.u[1], __ATOMIC_RELAXED, __HIP_MEMORY_SCOPE_AGENT);
        }
      __syncthreads();
      if (tid == 0) __hip_atomic_store(&pflag[bid], (uint32_t)(t+1), __ATOMIC_RELEASE, __HIP_MEMORY_SCOPE_AGENT);
      continue;
    }

    // owner: gather k-helper partials in ascending-k order (deterministic)
    if (tid == 0) for (int p = 1; p < ksp; ++p) wait_ge(&pflag[bid+p], (uint32_t)(t+1));
    __syncthreads();
    for (int p = 1; p < ksp; ++p) {
      int hs = (group==0) ? tl : ((group==1) ? (64 + tl*3 + (p-1)) : (256 + tl*3 + (p-1)));
      uint64_t* pb = (uint64_t*)(partials + (size_t)hs*4096) + tid*16;
      #pragma unroll
      for (int r = 0; r < 4; ++r)
        #pragma unroll
        for (int cq = 0; cq < 2; ++cq) {
          union { uint64_t u[2]; float f[4]; } cv;
          cv.u[0] = __hip_atomic_load(&pb[r*4+cq*2+0], __ATOMIC_RELAXED, __HIP_MEMORY_SCOPE_AGENT);
          cv.u[1] = __hip_atomic_load(&pb[r*4+cq*2+1], __ATOMIC_RELAXED, __HIP_MEMORY_SCOPE_AGENT);
          acc[r][cq*4+0] += cv.f[0]; acc[r][cq*4+1] += cv.f[1];
          acc[r][cq*4+2] += cv.f[2]; acc[r][cq*4+3] += cv.f[3];
        }
    }
    __syncthreads();
    if (tid == 0) __hip_atomic_store(&oflag[bid], (uint32_t)(t+1), __ATOMIC_RELEASE, __HIP_MEMORY_SCOPE_AGENT);

    if (group < 2) { lBits[tid] = 0; __syncthreads(); }

    // LIF: cur = acc + b (rn); v = 0.9*v + cur (mul+add rn, NO fma contraction,
    // matching np's BETA*vi + cur); spk = v > 1.0 strictly; v -= spk.
    #pragma unroll
    for (int r = 0; r < 4; ++r) {
      uint32_t msk = 0;
      float sv[8], vv8[8];
      #pragma unroll
      for (int c = 0; c < 8; ++c) {
        float cur = __fadd_rn(acc[r][c], bias[c]);
        float vv  = __fadd_rn(__fmul_rn(0.9f, vst[r][c]), cur);
        float s = (vv > 1.0f) ? 1.0f : 0.0f;
        vv = __fsub_rn(vv, s);
        vst[r][c] = vv;
        sv[c] = s; vv8[c] = vv;
        msk |= (s != 0.f) ? (1u << c) : 0u;
      }
      if (group == 2) {
        size_t o = ((size_t)(m0 + tm*4 + r)*TT + t)*DD2 + n0 + tn*8;
        *(float4*)(out + o)     = make_float4(sv[0], sv[1], sv[2], sv[3]);
        *(float4*)(out + o + 4) = make_float4(sv[4], sv[5], sv[6], sv[7]);
        size_t ov = (size_t)NB*TT*DD2 + o;
        *(float4*)(out + ov)     = make_float4(vv8[0], vv8[1], vv8[2], vv8[3]);
        *(float4*)(out + ov + 4) = make_float4(vv8[4], vv8[5], vv8[6], vv8[7]);
      } else if (msk) {
        atomicOr(&lBits[(tm*4 + r)*2 + (tn>>2)], msk << ((tn&3)*8));
      }
    }

    if (group < 2) {
      __syncthreads();
      {
        int row = tid >> 1, wz = tid & 1;
        __hip_atomic_store(&spkOut[((size_t)t*NB + m0+row)*64 + (n0>>5) + wz], lBits[tid],
                           __ATOMIC_RELAXED, __HIP_MEMORY_SCOPE_AGENT);
      }
      __syncthreads();
      if (tid == 0) __hip_atomic_fetch_add(&dOut[t], 1u, __ATOMIC_RELEASE, __HIP_MEMORY_SCOPE_AGENT);
    }
  }
}

extern "C" void kernel_launch(void* const* d_in, const int* in_sizes, int n_in,
                              void* d_out, int out_size, void* d_ws, size_t ws_size,
                              hipStream_t stream) {
  (void)in_sizes; (void)n_in; (void)out_size;
  float* outf = (float*)d_out;
  if (ws_size < WS_NEED_BYTES) {            // diagnostic: absmax ~41 => ws too small
    sentinel_kernel<<<1, 1, 0, stream>>>(outf);
    return;
  }
  const float* x  = (const float*)d_in[0];
  const float* W0 = (const float*)d_in[1];
  const float* b0 = (const float*)d_in[2];
  const float* W1 = (const float*)d_in[3];
  const float* b1 = (const float*)d_in[4];
  const float* W2 = (const float*)d_in[5];
  const float* b2 = (const float*)d_in[6];
  uint32_t* ws = (uint32_t*)d_ws;

  // zero flags (spikes/partials are write-before-read; flags gate everything)
  hipMemsetAsync(ws + FLG_OFF, 0, 1280 * sizeof(uint32_t), stream);

  snn_kernel<<<512, 128, 0, stream>>>(x, W0, b0, W1, b1, W2, b2, outf, ws);
}